// Round 6
// baseline (514.251 us; speedup 1.0000x reference)
//
#include <hip/hip_runtime.h>
#include <cstdint>
#include <cstddef>

#define NOBJ 32
#define NP   992
#define DD   256
#define SP   196   // 14*14
#define OC   151
#define RC   51
#define RED  64
#define KIN  4251  // 4096 + 151 + 4
#define CH   128   // emb1 k-chunks
#define KPC  34    // ceil(4251/128)

// ---- ws layout (float offsets) ----
#define OFF_PART   0u         // 128*32*256 = 1048576
#define OFF_OBJF   1048576u   // 8192
#define OFF_SALL   1056768u   // 992*768 = 761856
#define OFF_RELF   1818624u   // 253952
#define OFF_H      2072576u   // 262144
#define OFF_W2T    2334720u   // (unused now)
#define OFF_WC1T   2400256u   // (unused now)
#define OFF_WC2T   2596864u   // (unused now)
#define OFF_WGT    2662400u   // (unused now)
#define OFF_FC1WT  2727936u   // (unused now)
#define OFF_FC2WT  2777088u   // (unused now)
#define OFF_WOPT   2826240u   // 38656
#define OFF_WRPT   2864896u   // 13056

#define TR_TOT 51712   // WopT (38656) + WrpT (13056) only

#define TCH  32        // channels per union tile
#define NTIL 8         // 256 / TCH
#define TF4  1568      // TCH*SP/4 float4 per tile

// ============ K_PRE: union(0..991) + emb1(992..1119) + transpose(1120..1183)
// Round-1 union structure (measured best; rounds 2-4 regressions documented).
// Transpose branch now only WopT/WrpT: mid2 reads original layouts coalesced.
__global__ void __launch_bounds__(256, 5)
k_pre(const float* __restrict__ uf,
      const float* __restrict__ bbox,
      const int* __restrict__ pairs,
      const float* __restrict__ roi,
      const float* __restrict__ logits,
      const float* __restrict__ W1,
      const float* __restrict__ Wop, const float* __restrict__ Wrp,
      float* __restrict__ sAll, float* __restrict__ part,
      float* __restrict__ WopT, float* __restrict__ WrpT) {
  const int b = blockIdx.x, t = threadIdx.x;
  if (b < NP) {
    // ---- union masked means: 32-ch tiles, reg-staged prefetch, shfl reduce
    const int p = b;
    __shared__ __align__(16) float buf[TCH * SP + 28];  // 25200 B (+28f slack)
    __shared__ __align__(16) float mS[224];             // masks padded to 224
    __shared__ __align__(16) float mO[224];
    __shared__ __align__(16) float mB[224];
    if (t < 224) {
      float sm = 0.f, om = 0.f, bm = 0.f;
      if (t < SP) {
        int si = pairs[2 * p], oi = pairs[2 * p + 1];
        float sx1 = bbox[si * 4 + 0], sy1 = bbox[si * 4 + 1];
        float sx2 = bbox[si * 4 + 2], sy2 = bbox[si * 4 + 3];
        float ox1 = bbox[oi * 4 + 0], oy1 = bbox[oi * 4 + 1];
        float ox2 = bbox[oi * 4 + 2], oy2 = bbox[oi * 4 + 3];
        float ux = fminf(sx1, ox1), uy = fminf(sy1, oy1);
        float xr = 14.f / fmaxf(sx2 - ux, ox2 - ux);
        float yr = 14.f / fmaxf(sy2 - uy, oy2 - uy);
        float xs0 = rintf((sx1 - ux) * xr), xs1 = rintf((sx2 - ux) * xr);
        float xo0 = rintf((ox1 - ux) * xr), xo1 = rintf((ox2 - ux) * xr);
        float ys0 = rintf((sy1 - uy) * yr), ys1 = rintf((sy2 - uy) * yr);
        float yo0 = rintf((oy1 - uy) * yr), yo1 = rintf((oy2 - uy) * yr);
        int a = t / 14, bb = t - a * 14;
        float fa = (float)a, fb = (float)bb;
        sm = (fa >= xs0 && fa < xs1 && fb >= ys0 && fb < ys1) ? 1.f : 0.f;
        om = (fa >= xo0 && fa < xo1 && fb >= yo0 && fb < yo1) ? 1.f : 0.f;
        bm = fminf(fmaxf(1.f - sm - om, 0.f), 1.f);
      }
      mS[t] = sm; mO[t] = om; mB[t] = bm;
    }
    if (t < 28) buf[TCH * SP + t] = 0.f;   // zero slack (slice 7 of ch 31 reads it)
    // prologue: tile 0 direct copy (coalesced)
    const float4* base4 = (const float4*)(uf + (size_t)p * (DD * SP));
    {
      const float4* src = base4 + t;
      float4* dst = (float4*)buf + t;
      dst[0] = src[0];     dst[256] = src[256];   dst[512] = src[512];
      dst[768] = src[768]; dst[1024] = src[1024]; dst[1280] = src[1280];
      if (t < 32) dst[1536] = src[1536];
    }
    __syncthreads();
    const int cl = t >> 3, o = t & 7;          // channel-in-tile, 28-float slice
    const float* row = buf + cl * SP + o * 28; // 16B-aligned (784/112-byte steps)
    const float* msp = mS + o * 28;
    const float* mop = mO + o * 28;
    const float* mbp = mB + o * 28;
    const float inv = 1.f / 196.f;
    float4 s0, s1, s2, s3, s4, s5, s6 = {0.f, 0.f, 0.f, 0.f};
#pragma unroll 1
    for (int ti = 0; ti < NTIL; ++ti) {
      if (ti < NTIL - 1) {
        const float4* src = base4 + (ti + 1) * TF4 + t;
        s0 = src[0];     s1 = src[256];   s2 = src[512];
        s3 = src[768];   s4 = src[1024];  s5 = src[1280];
        if (t < 32) s6 = src[1536];
      }
      float aS = 0.f, aO = 0.f, aB = 0.f;
#pragma unroll
      for (int j = 0; j < 7; ++j) {
        float4 v = *(const float4*)&row[4 * j];
        float4 x = *(const float4*)&msp[4 * j];
        float4 y = *(const float4*)&mop[4 * j];
        float4 z = *(const float4*)&mbp[4 * j];
        aS += v.x * x.x + v.y * x.y + v.z * x.z + v.w * x.w;
        aO += v.x * y.x + v.y * y.y + v.z * y.z + v.w * y.w;
        aB += v.x * z.x + v.y * z.y + v.z * z.z + v.w * z.w;
      }
      aS += __shfl_xor(aS, 1); aS += __shfl_xor(aS, 2); aS += __shfl_xor(aS, 4);
      aO += __shfl_xor(aO, 1); aO += __shfl_xor(aO, 2); aO += __shfl_xor(aO, 4);
      aB += __shfl_xor(aB, 1); aB += __shfl_xor(aB, 2); aB += __shfl_xor(aB, 4);
      const int ch = ti * TCH + cl;
      if (o == 0)      sAll[(size_t)p * 768 + ch]       = aS * inv;
      else if (o == 1) sAll[(size_t)p * 768 + 256 + ch] = aO * inv;
      else if (o == 2) sAll[(size_t)p * 768 + 512 + ch] = aB * inv;
      if (ti < NTIL - 1) {
        __syncthreads();
        float4* dst = (float4*)buf + t;
        dst[0] = s0;     dst[256] = s1;   dst[512] = s2;
        dst[768] = s3;   dst[1024] = s4;  dst[1280] = s5;
        if (t < 32) dst[1536] = s6;
        __syncthreads();
      }
    }
  } else if (b < NP + CH) {
    // ---- emb1 split-K partial ----
    const int chunk = b - NP;
    int k0 = chunk * KPC;
    int k1 = k0 + KPC; if (k1 > KIN) k1 = KIN;
    float acc[NOBJ];
#pragma unroll
    for (int i = 0; i < NOBJ; ++i) acc[i] = 0.f;
#pragma unroll 2
    for (int k = k0; k < k1; ++k) {
      float w = W1[(size_t)k * DD + t];
      const float* xp; int stride;
      if (k < 4096)            { xp = roi    + k;               stride = 4096; }
      else if (k < 4096 + OC)  { xp = logits + (k - 4096);      stride = OC;   }
      else                     { xp = bbox   + (k - 4096 - OC); stride = 4;    }
#pragma unroll
      for (int i = 0; i < NOBJ; ++i) { acc[i] += xp[0] * w; xp += stride; }
    }
    float* pout = part + (size_t)chunk * (NOBJ * DD) + t;
#pragma unroll
    for (int i = 0; i < NOBJ; ++i) pout[i * DD] = acc[i];
  } else {
    // ---- head-weight transposes only (WopT, WrpT) ----
    for (int o = (b - NP - CH) * 256 + t; o < TR_TOT; o += 64 * 256) {
      float v; float* dst;
      if (o < 38656) { int q = o;         v = Wop[(q & 255) * OC + (q >> 8)]; dst = WopT + q; }
      else           { int q = o - 38656; v = Wrp[(q & 255) * RC + (q >> 8)]; dst = WrpT + q; }
      *dst = v;
    }
  }
}

// ============ K_MID2: rel path = 1 wave per pair, lane owns 4 output cols ==
// All weight reads COALESCED from ORIGINAL layouts (lane l reads W[k][4l..4l+3],
// consecutive lanes -> consecutive 16B). Activations broadcast from wave-private
// LDS (uniform addr, conflict-free). Replaces the old per-col-per-thread scheme
// whose per-lane-stride weight reads serialized ~64 cache lines per instr.
__global__ void __launch_bounds__(256, 4)
k_mid2(const float* __restrict__ sAll,
       const float* __restrict__ f1w, const float* __restrict__ f1b,
       const float* __restrict__ f2w, const float* __restrict__ f2b,
       const float* __restrict__ Wc1, const float* __restrict__ bc1,
       const float* __restrict__ Wc2, const float* __restrict__ bc2,
       const float* __restrict__ Wg,
       const float* __restrict__ part, const float* __restrict__ b1,
       const float* __restrict__ W2,  const float* __restrict__ b2,
       float* __restrict__ relf, float* __restrict__ objf,
       float* __restrict__ H) {
  const int b = blockIdx.x, t = threadIdx.x;
  __shared__ __align__(16) float sg[4][768];
  __shared__ __align__(16) float ha[4][192];
  __shared__ __align__(16) float h2[4][256];
  __shared__ __align__(16) float hob[256];
  __shared__ __align__(16) float eob[256];
  if (b < NP / 4) {
    const int w = t >> 6, l = t & 63;       // wave = pair, lane owns cols 4l..4l+3
    const int r = b * 4 + w;
    {   // stage this pair's sAll row (768 floats, coalesced)
      const float4* src = (const float4*)(sAll + (size_t)r * 768);
      float4* dst = (float4*)&sg[w][0];
      dst[l] = src[l]; dst[64 + l] = src[64 + l]; dst[128 + l] = src[128 + l];
    }
    __syncthreads();
    // ---- P1: att fc1 (3 branches, lane l owns red=l) ----
    {
      float a0 = 0.f, a1 = 0.f, a2 = 0.f;
      const float* w0 = f1w + l;            // f1w[br][d][red]: + d*64
      const float* w1 = f1w + 16384 + l;
      const float* w2 = f1w + 32768 + l;
#pragma unroll 4
      for (int d4 = 0; d4 < 64; ++d4) {
        float4 x0 = *((const float4*)&sg[w][0]   + d4);
        float4 x1 = *((const float4*)&sg[w][256] + d4);
        float4 x2 = *((const float4*)&sg[w][512] + d4);
        int d = 4 * d4;
        a0 += x0.x * w0[d * 64] + x0.y * w0[(d + 1) * 64] +
              x0.z * w0[(d + 2) * 64] + x0.w * w0[(d + 3) * 64];
        a1 += x1.x * w1[d * 64] + x1.y * w1[(d + 1) * 64] +
              x1.z * w1[(d + 2) * 64] + x1.w * w1[(d + 3) * 64];
        a2 += x2.x * w2[d * 64] + x2.y * w2[(d + 1) * 64] +
              x2.z * w2[(d + 2) * 64] + x2.w * w2[(d + 3) * 64];
      }
      ha[w][l]       = fmaxf(a0 + f1b[l], 0.f);
      ha[w][64 + l]  = fmaxf(a1 + f1b[64 + l], 0.f);
      ha[w][128 + l] = fmaxf(a2 + f1b[128 + l], 0.f);
    }
    __syncthreads();
    // ---- P2: att fc2 + sigmoid gate (lane cols 4l..4l+3 per branch) ----
#pragma unroll
    for (int br = 0; br < 3; ++br) {
      float ax = 0.f, ay = 0.f, az = 0.f, aw = 0.f;
      const float4* wp = (const float4*)(f2w + br * 16384) + l;  // [red][d]
#pragma unroll 8
      for (int red = 0; red < 64; ++red) {
        float x = ha[w][br * 64 + red];
        float4 wv = wp[red * 64];
        ax += x * wv.x; ay += x * wv.y; az += x * wv.z; aw += x * wv.w;
      }
      float4 bb = *((const float4*)(f2b + br * 256) + l);
      float4 sv = *((float4*)&sg[w][br * 256] + l);
      sv.x *= 1.f / (1.f + expf(-(ax + bb.x)));
      sv.y *= 1.f / (1.f + expf(-(ay + bb.y)));
      sv.z *= 1.f / (1.f + expf(-(az + bb.z)));
      sv.w *= 1.f / (1.f + expf(-(aw + bb.w)));
      *((float4*)&sg[w][br * 256] + l) = sv;
    }
    __syncthreads();
    // ---- P3: rel fc1 768->256 relu ----
    {
      float ax = 0.f, ay = 0.f, az = 0.f, aw = 0.f;
      const float4* wp = (const float4*)Wc1 + l;                 // [k][c]
#pragma unroll 4
      for (int k4 = 0; k4 < 192; ++k4) {
        float4 x = *((const float4*)&sg[w][0] + k4);
        int k = 4 * k4;
        float4 v0 = wp[(size_t)k * 64], v1 = wp[(size_t)(k + 1) * 64];
        float4 v2 = wp[(size_t)(k + 2) * 64], v3 = wp[(size_t)(k + 3) * 64];
        ax += x.x * v0.x + x.y * v1.x + x.z * v2.x + x.w * v3.x;
        ay += x.x * v0.y + x.y * v1.y + x.z * v2.y + x.w * v3.y;
        az += x.x * v0.z + x.y * v1.z + x.z * v2.z + x.w * v3.z;
        aw += x.x * v0.w + x.y * v1.w + x.z * v2.w + x.w * v3.w;
      }
      float4 bb = *((const float4*)bc1 + l);
      float4 hv;
      hv.x = fmaxf(ax + bb.x, 0.f); hv.y = fmaxf(ay + bb.y, 0.f);
      hv.z = fmaxf(az + bb.z, 0.f); hv.w = fmaxf(aw + bb.w, 0.f);
      *((float4*)&h2[w][0] + l) = hv;
    }
    __syncthreads();
    // ---- P4: rel fc2 -> relf + stash into sg[w][0..255] ----
    {
      float ax = 0.f, ay = 0.f, az = 0.f, aw = 0.f;
      const float4* wp = (const float4*)Wc2 + l;
#pragma unroll 4
      for (int k4 = 0; k4 < 64; ++k4) {
        float4 x = *((const float4*)&h2[w][0] + k4);
        int k = 4 * k4;
        float4 v0 = wp[k * 64], v1 = wp[(k + 1) * 64];
        float4 v2 = wp[(k + 2) * 64], v3 = wp[(k + 3) * 64];
        ax += x.x * v0.x + x.y * v1.x + x.z * v2.x + x.w * v3.x;
        ay += x.x * v0.y + x.y * v1.y + x.z * v2.y + x.w * v3.y;
        az += x.x * v0.z + x.y * v1.z + x.z * v2.z + x.w * v3.z;
        aw += x.x * v0.w + x.y * v1.w + x.z * v2.w + x.w * v3.w;
      }
      float4 bb = *((const float4*)bc2 + l);
      float4 v; v.x = ax + bb.x; v.y = ay + bb.y; v.z = az + bb.z; v.w = aw + bb.w;
      *(float4*)(relf + (size_t)r * DD + 4 * l) = v;
      *((float4*)&sg[w][0] + l) = v;
    }
    __syncthreads();
    // ---- P5: H_rel = relf @ Wg ----
    {
      float ax = 0.f, ay = 0.f, az = 0.f, aw = 0.f;
      const float4* wp = (const float4*)Wg + l;
#pragma unroll 4
      for (int k4 = 0; k4 < 64; ++k4) {
        float4 x = *((const float4*)&sg[w][0] + k4);
        int k = 4 * k4;
        float4 v0 = wp[k * 64], v1 = wp[(k + 1) * 64];
        float4 v2 = wp[(k + 2) * 64], v3 = wp[(k + 3) * 64];
        ax += x.x * v0.x + x.y * v1.x + x.z * v2.x + x.w * v3.x;
        ay += x.x * v0.y + x.y * v1.y + x.z * v2.y + x.w * v3.y;
        az += x.x * v0.z + x.y * v1.z + x.z * v2.z + x.w * v3.z;
        aw += x.x * v0.w + x.y * v1.w + x.z * v2.w + x.w * v3.w;
      }
      float4 v; v.x = ax; v.y = ay; v.z = az; v.w = aw;
      *(float4*)(H + (size_t)(NOBJ + r) * DD + 4 * l) = v;
    }
  } else {
    // ---- emb2 + H_obj: 1 object per block, coalesced original W2/Wg ----
    const int i = b - NP / 4;   // 0..31
    float s[8];
#pragma unroll
    for (int u = 0; u < 8; ++u) s[u] = 0.f;
#pragma unroll
    for (int c0 = 0; c0 < CH; c0 += 8) {
#pragma unroll
      for (int u = 0; u < 8; ++u)
        s[u] += part[(size_t)(c0 + u) * (NOBJ * DD) + i * DD + t];
    }
    float tot = ((s[0] + s[1]) + (s[2] + s[3])) + ((s[4] + s[5]) + (s[6] + s[7]));
    hob[t] = fmaxf(tot + b1[t], 0.f);
    __syncthreads();
    {
      float a = 0.f;
#pragma unroll 4
      for (int k4 = 0; k4 < 64; ++k4) {
        float4 hv = *((const float4*)hob + k4);
        int k = 4 * k4;
        a += hv.x * W2[k * 256 + t]       + hv.y * W2[(k + 1) * 256 + t]
           + hv.z * W2[(k + 2) * 256 + t] + hv.w * W2[(k + 3) * 256 + t];
      }
      float v = a + b2[t];
      objf[i * DD + t] = v;
      eob[t] = v;
    }
    __syncthreads();
    {
      float a = 0.f;
#pragma unroll 4
      for (int k4 = 0; k4 < 64; ++k4) {
        float4 ev = *((const float4*)eob + k4);
        int k = 4 * k4;
        a += ev.x * Wg[k * 256 + t]       + ev.y * Wg[(k + 1) * 256 + t]
           + ev.z * Wg[(k + 2) * 256 + t] + ev.w * Wg[(k + 3) * 256 + t];
      }
      H[(size_t)i * DD + t] = a;
    }
  }
}

// ============ K_HEADS: rel(0..247, 4 pairs) + obj(248..279), 1024 thr ======
__global__ void __launch_bounds__(1024, 1)
k_heads(const float* __restrict__ H, const float* __restrict__ objf,
        const float* __restrict__ relf, const int* __restrict__ pairs,
        const float* __restrict__ bg,
        const float* __restrict__ WopT, const float* __restrict__ bop,
        const float* __restrict__ WrpT, const float* __restrict__ brp,
        float* __restrict__ out) {
  const int b = blockIdx.x, t = threadIdx.x;
  const int p = t >> 8, tt = t & 255;
  if (b < NP / 4) {
    __shared__ __align__(16) float gr[4][DD];
    __shared__ float red[4][4][64];
    const int r = b * 4 + p;
    int si = pairs[2 * r], oi = pairs[2 * r + 1];
    float hsum = H[si * DD + tt] + H[oi * DD + tt] + H[(size_t)(NOBJ + r) * DD + tt];
    gr[p][tt] = fmaxf(hsum * (1.f / 3.f) + bg[tt], 0.f) + relf[(size_t)r * DD + tt];
    __syncthreads();
    const int q = tt >> 6, c = tt & 63;
    float a = 0.f;
    if (c < RC) {
      const float4* w4 = (const float4*)(WrpT + c * 256 + q * 64);
#pragma unroll
      for (int j = 0; j < 16; ++j) {
        float4 wv = w4[j];
        float4 gv = *(const float4*)&gr[p][q * 64 + 4 * j];
        a += gv.x * wv.x + gv.y * wv.y + gv.z * wv.z + gv.w * wv.w;
      }
    }
    red[p][q][c] = a;
    __syncthreads();
    if (tt < RC)
      out[NOBJ * OC + (size_t)r * RC + tt] =
          red[p][0][tt] + red[p][1][tt] + red[p][2][tt] + red[p][3][tt] + brp[tt];
  } else {
    const int i = b - NP / 4;   // 0..31
    const int slice = p;
    __shared__ int2 pr[NP];
    __shared__ float red2[4][DD];
    __shared__ __align__(16) float gro[DD];
    const int2* p2 = (const int2*)pairs;
    for (int r = t; r < NP; r += 1024) pr[r] = p2[r];
    __syncthreads();
    float acc = 0.f;
    if (slice == 0) {
#pragma unroll 8
      for (int j = 0; j < NOBJ; ++j) acc += H[j * DD + tt];
    }
    const int rbeg = slice * 248;
#pragma unroll 8
    for (int r = rbeg; r < rbeg + 248; ++r) {
      int2 q = pr[r];
      float v = H[(size_t)(NOBJ + r) * DD + tt];
      if (q.x == i || q.y == i) acc += v;
    }
    red2[slice][tt] = acc;
    __syncthreads();
    if (t < DD) {
      float pre = (red2[0][t] + red2[1][t] + red2[2][t] + red2[3][t]) * (1.f / 94.f);
      gro[t] = fmaxf(pre + bg[t], 0.f) + objf[i * DD + t];
    }
    __syncthreads();
    float hsum = 0.f;
    if (tt < OC) {
      const float4* w4 = (const float4*)(WopT + tt * 256 + slice * 64);
#pragma unroll
      for (int j = 0; j < 16; ++j) {
        float4 wv = w4[j];
        float4 gv = *(const float4*)&gro[slice * 64 + 4 * j];
        hsum += gv.x * wv.x + gv.y * wv.y + gv.z * wv.z + gv.w * wv.w;
      }
    }
    red2[slice][tt] = hsum;
    __syncthreads();
    if (t < OC)
      out[i * OC + t] = red2[0][t] + red2[1][t] + red2[2][t] + red2[3][t] + bop[t];
  }
}

extern "C" void kernel_launch(void* const* d_in, const int* in_sizes, int n_in,
                              void* d_out, int out_size, void* d_ws, size_t ws_size,
                              hipStream_t stream) {
  const float* roi   = (const float*)d_in[0];
  const float* bbox  = (const float*)d_in[1];
  const float* logit = (const float*)d_in[2];
  const float* uf    = (const float*)d_in[3];
  const int*   pairs = (const int*)d_in[4];
  const float* W1    = (const float*)d_in[5];
  const float* b1    = (const float*)d_in[6];
  const float* W2    = (const float*)d_in[7];
  const float* b2    = (const float*)d_in[8];
  const float* fc1w  = (const float*)d_in[9];
  const float* fc1b  = (const float*)d_in[10];
  const float* fc2w  = (const float*)d_in[11];
  const float* fc2b  = (const float*)d_in[12];
  const float* Wc1   = (const float*)d_in[13];
  const float* bc1   = (const float*)d_in[14];
  const float* Wc2   = (const float*)d_in[15];
  const float* bc2   = (const float*)d_in[16];
  const float* Wg    = (const float*)d_in[17];
  const float* bg    = (const float*)d_in[18];
  const float* Wop   = (const float*)d_in[19];
  const float* bop   = (const float*)d_in[20];
  const float* Wrp   = (const float*)d_in[21];
  const float* brp   = (const float*)d_in[22];

  float* ws    = (float*)d_ws;
  float* part  = ws + OFF_PART;
  float* objf  = ws + OFF_OBJF;
  float* sAll  = ws + OFF_SALL;
  float* relf  = ws + OFF_RELF;
  float* Hbuf  = ws + OFF_H;
  float* WopT  = ws + OFF_WOPT;
  float* WrpT  = ws + OFF_WRPT;
  float* out   = (float*)d_out;

  k_pre<<<NP + CH + 64, 256, 0, stream>>>(uf, bbox, pairs, roi, logit, W1,
                                          Wop, Wrp, sAll, part, WopT, WrpT);
  k_mid2<<<NP / 4 + NOBJ, 256, 0, stream>>>(sAll, fc1w, fc1b, fc2w, fc2b,
                                            Wc1, bc1, Wc2, bc2, Wg,
                                            part, b1, W2, b2, relf, objf, Hbuf);
  k_heads<<<NP / 4 + NOBJ, 1024, 0, stream>>>(Hbuf, objf, relf, pairs, bg,
                                              WopT, bop, WrpT, brp, out);
}

// Round 7
// 454.468 us; speedup vs baseline: 1.1315x; 1.1315x over previous
//
#include <hip/hip_runtime.h>
#include <cstdint>
#include <cstddef>

#define NOBJ 32
#define NP   992
#define DD   256
#define SP   196   // 14*14
#define OC   151
#define RC   51
#define RED  64
#define KIN  4251  // 4096 + 151 + 4
#define CH   128   // emb1 k-chunks
#define KPC  34    // ceil(4251/128)

// ---- ws layout (float offsets) ----
#define OFF_PART   0u         // 128*32*256 = 1048576
#define OFF_OBJF   1048576u   // 8192
#define OFF_SALL   1056768u   // 992*768 = 761856
#define OFF_RELF   1818624u   // 253952
#define OFF_H      2072576u   // 262144
#define OFF_WOPT   2826240u   // 38656
#define OFF_WRPT   2864896u   // 13056

#define TR_TOT 51712   // WopT (38656) + WrpT (13056) only

#define TCH  32        // channels per union tile
#define NTIL 8         // 256 / TCH
#define TF4  1568      // TCH*SP/4 float4 per tile

// ============ K_PRE: union(0..991) + emb1(992..1119) + transpose(1120..1183)
// Round-1 union structure (measured best; rounds 2-4 regressions documented).
__global__ void __launch_bounds__(256, 5)
k_pre(const float* __restrict__ uf,
      const float* __restrict__ bbox,
      const int* __restrict__ pairs,
      const float* __restrict__ roi,
      const float* __restrict__ logits,
      const float* __restrict__ W1,
      const float* __restrict__ Wop, const float* __restrict__ Wrp,
      float* __restrict__ sAll, float* __restrict__ part,
      float* __restrict__ WopT, float* __restrict__ WrpT) {
  const int b = blockIdx.x, t = threadIdx.x;
  if (b < NP) {
    // ---- union masked means: 32-ch tiles, reg-staged prefetch, shfl reduce
    const int p = b;
    __shared__ __align__(16) float buf[TCH * SP + 28];  // 25200 B (+28f slack)
    __shared__ __align__(16) float mS[224];             // masks padded to 224
    __shared__ __align__(16) float mO[224];
    __shared__ __align__(16) float mB[224];
    if (t < 224) {
      float sm = 0.f, om = 0.f, bm = 0.f;
      if (t < SP) {
        int si = pairs[2 * p], oi = pairs[2 * p + 1];
        float sx1 = bbox[si * 4 + 0], sy1 = bbox[si * 4 + 1];
        float sx2 = bbox[si * 4 + 2], sy2 = bbox[si * 4 + 3];
        float ox1 = bbox[oi * 4 + 0], oy1 = bbox[oi * 4 + 1];
        float ox2 = bbox[oi * 4 + 2], oy2 = bbox[oi * 4 + 3];
        float ux = fminf(sx1, ox1), uy = fminf(sy1, oy1);
        float xr = 14.f / fmaxf(sx2 - ux, ox2 - ux);
        float yr = 14.f / fmaxf(sy2 - uy, oy2 - uy);
        float xs0 = rintf((sx1 - ux) * xr), xs1 = rintf((sx2 - ux) * xr);
        float xo0 = rintf((ox1 - ux) * xr), xo1 = rintf((ox2 - ux) * xr);
        float ys0 = rintf((sy1 - uy) * yr), ys1 = rintf((sy2 - uy) * yr);
        float yo0 = rintf((oy1 - uy) * yr), yo1 = rintf((oy2 - uy) * yr);
        int a = t / 14, bb = t - a * 14;
        float fa = (float)a, fb = (float)bb;
        sm = (fa >= xs0 && fa < xs1 && fb >= ys0 && fb < ys1) ? 1.f : 0.f;
        om = (fa >= xo0 && fa < xo1 && fb >= yo0 && fb < yo1) ? 1.f : 0.f;
        bm = fminf(fmaxf(1.f - sm - om, 0.f), 1.f);
      }
      mS[t] = sm; mO[t] = om; mB[t] = bm;
    }
    if (t < 28) buf[TCH * SP + t] = 0.f;   // zero slack (slice 7 of ch 31 reads it)
    const float4* base4 = (const float4*)(uf + (size_t)p * (DD * SP));
    {
      const float4* src = base4 + t;
      float4* dst = (float4*)buf + t;
      dst[0] = src[0];     dst[256] = src[256];   dst[512] = src[512];
      dst[768] = src[768]; dst[1024] = src[1024]; dst[1280] = src[1280];
      if (t < 32) dst[1536] = src[1536];
    }
    __syncthreads();
    const int cl = t >> 3, o = t & 7;          // channel-in-tile, 28-float slice
    const float* row = buf + cl * SP + o * 28; // 16B-aligned
    const float* msp = mS + o * 28;
    const float* mop = mO + o * 28;
    const float* mbp = mB + o * 28;
    const float inv = 1.f / 196.f;
    float4 s0, s1, s2, s3, s4, s5, s6 = {0.f, 0.f, 0.f, 0.f};
#pragma unroll 1
    for (int ti = 0; ti < NTIL; ++ti) {
      if (ti < NTIL - 1) {
        const float4* src = base4 + (ti + 1) * TF4 + t;
        s0 = src[0];     s1 = src[256];   s2 = src[512];
        s3 = src[768];   s4 = src[1024];  s5 = src[1280];
        if (t < 32) s6 = src[1536];
      }
      float aS = 0.f, aO = 0.f, aB = 0.f;
#pragma unroll
      for (int j = 0; j < 7; ++j) {
        float4 v = *(const float4*)&row[4 * j];
        float4 x = *(const float4*)&msp[4 * j];
        float4 y = *(const float4*)&mop[4 * j];
        float4 z = *(const float4*)&mbp[4 * j];
        aS += v.x * x.x + v.y * x.y + v.z * x.z + v.w * x.w;
        aO += v.x * y.x + v.y * y.y + v.z * y.z + v.w * y.w;
        aB += v.x * z.x + v.y * z.y + v.z * z.z + v.w * z.w;
      }
      aS += __shfl_xor(aS, 1); aS += __shfl_xor(aS, 2); aS += __shfl_xor(aS, 4);
      aO += __shfl_xor(aO, 1); aO += __shfl_xor(aO, 2); aO += __shfl_xor(aO, 4);
      aB += __shfl_xor(aB, 1); aB += __shfl_xor(aB, 2); aB += __shfl_xor(aB, 4);
      const int ch = ti * TCH + cl;
      if (o == 0)      sAll[(size_t)p * 768 + ch]       = aS * inv;
      else if (o == 1) sAll[(size_t)p * 768 + 256 + ch] = aO * inv;
      else if (o == 2) sAll[(size_t)p * 768 + 512 + ch] = aB * inv;
      if (ti < NTIL - 1) {
        __syncthreads();
        float4* dst = (float4*)buf + t;
        dst[0] = s0;     dst[256] = s1;   dst[512] = s2;
        dst[768] = s3;   dst[1024] = s4;  dst[1280] = s5;
        if (t < 32) dst[1536] = s6;
        __syncthreads();
      }
    }
  } else if (b < NP + CH) {
    // ---- emb1 split-K partial ----
    const int chunk = b - NP;
    int k0 = chunk * KPC;
    int k1 = k0 + KPC; if (k1 > KIN) k1 = KIN;
    float acc[NOBJ];
#pragma unroll
    for (int i = 0; i < NOBJ; ++i) acc[i] = 0.f;
#pragma unroll 2
    for (int k = k0; k < k1; ++k) {
      float w = W1[(size_t)k * DD + t];
      const float* xp; int stride;
      if (k < 4096)            { xp = roi    + k;               stride = 4096; }
      else if (k < 4096 + OC)  { xp = logits + (k - 4096);      stride = OC;   }
      else                     { xp = bbox   + (k - 4096 - OC); stride = 4;    }
#pragma unroll
      for (int i = 0; i < NOBJ; ++i) { acc[i] += xp[0] * w; xp += stride; }
    }
    float* pout = part + (size_t)chunk * (NOBJ * DD) + t;
#pragma unroll
    for (int i = 0; i < NOBJ; ++i) pout[i * DD] = acc[i];
  } else {
    // ---- head-weight transposes only (WopT, WrpT) ----
    for (int o = (b - NP - CH) * 256 + t; o < TR_TOT; o += 64 * 256) {
      float v; float* dst;
      if (o < 38656) { int q = o;         v = Wop[(q & 255) * OC + (q >> 8)]; dst = WopT + q; }
      else           { int q = o - 38656; v = Wrp[(q & 255) * RC + (q >> 8)]; dst = WrpT + q; }
      *dst = v;
    }
  }
}

// 8-step dot: 8 coalesced weight loads (stride STR floats) x 2 pairs of
// float4 activation broadcasts from LDS. 8 independent loads in flight.
#define DOT8(WP, STR, X0, X1, K, A0, A1)                                      \
  { float w0v = (WP)[(size_t)((K) + 0) * (STR)],                              \
          w1v = (WP)[(size_t)((K) + 1) * (STR)],                              \
          w2v = (WP)[(size_t)((K) + 2) * (STR)],                              \
          w3v = (WP)[(size_t)((K) + 3) * (STR)],                              \
          w4v = (WP)[(size_t)((K) + 4) * (STR)],                              \
          w5v = (WP)[(size_t)((K) + 5) * (STR)],                              \
          w6v = (WP)[(size_t)((K) + 6) * (STR)],                              \
          w7v = (WP)[(size_t)((K) + 7) * (STR)];                              \
    float4 xa0 = *(const float4*)&(X0)[(K)];                                  \
    float4 xb0 = *(const float4*)&(X0)[(K) + 4];                              \
    float4 xa1 = *(const float4*)&(X1)[(K)];                                  \
    float4 xb1 = *(const float4*)&(X1)[(K) + 4];                              \
    A0 += xa0.x * w0v + xa0.y * w1v + xa0.z * w2v + xa0.w * w3v               \
        + xb0.x * w4v + xb0.y * w5v + xb0.z * w6v + xb0.w * w7v;              \
    A1 += xa1.x * w0v + xa1.y * w1v + xa1.z * w2v + xa1.w * w3v               \
        + xb1.x * w4v + xb1.y * w5v + xb1.z * w6v + xb1.w * w7v; }

// ============ K_MID2: rel = 2 pairs/block, thread owns 1 output column =====
// Weight rows read coalesced from ORIGINAL layouts, reused across both pairs
// in registers (halves L2 traffic vs wave-per-pair). 528 blocks ~= 2/CU,
// ~8 waves/CU; k-unroll 8 gives 8 loads in flight per wave.
__global__ void __launch_bounds__(256, 4)
k_mid2(const float* __restrict__ sAll,
       const float* __restrict__ f1w, const float* __restrict__ f1b,
       const float* __restrict__ f2w, const float* __restrict__ f2b,
       const float* __restrict__ Wc1, const float* __restrict__ bc1,
       const float* __restrict__ Wc2, const float* __restrict__ bc2,
       const float* __restrict__ Wg,
       const float* __restrict__ part, const float* __restrict__ b1,
       const float* __restrict__ W2,  const float* __restrict__ b2,
       float* __restrict__ relf, float* __restrict__ objf,
       float* __restrict__ H) {
  const int b = blockIdx.x, t = threadIdx.x;
  __shared__ __align__(16) float sg[2][768];
  __shared__ __align__(16) float ha[2][192];
  __shared__ __align__(16) float h2[2][256];
  __shared__ __align__(16) float rf[2][256];
  __shared__ __align__(16) float hob[256];
  __shared__ __align__(16) float eob[256];
  if (b < NP / 2) {
    const int r0 = b * 2;
    const int tt = t;
    // stage both pairs' sAll rows (coalesced float4)
    for (int j = t; j < 384; j += 256) {
      int pr = j / 192, off = j - pr * 192;
      ((float4*)&sg[pr][0])[off] =
          ((const float4*)(sAll + (size_t)(r0 + pr) * 768))[off];
    }
    __syncthreads();
    // ---- P1: att fc1 (out 192, K=256 per branch) ----
    if (tt < 192) {
      const int br = tt >> 6;
      const float* wp = f1w + br * 16384 + (tt & 63);   // f1w[br][k][rc]
      const float* x0 = &sg[0][br * 256];
      const float* x1 = &sg[1][br * 256];
      float a0 = 0.f, a1 = 0.f;
      for (int k8 = 0; k8 < 32; ++k8) DOT8(wp, 64, x0, x1, k8 * 8, a0, a1)
      float bb = f1b[tt];
      ha[0][tt] = fmaxf(a0 + bb, 0.f);
      ha[1][tt] = fmaxf(a1 + bb, 0.f);
    }
    __syncthreads();
    // ---- P2: att fc2 + sigmoid gate (out 768, K=64 per branch) ----
#pragma unroll
    for (int br = 0; br < 3; ++br) {
      const float* wp = f2w + br * 16384 + tt;          // f2w[br][red][c]
      const float* x0 = &ha[0][br * 64];
      const float* x1 = &ha[1][br * 64];
      float a0 = 0.f, a1 = 0.f;
      for (int r8 = 0; r8 < 8; ++r8) DOT8(wp, 256, x0, x1, r8 * 8, a0, a1)
      float bb = f2b[br * 256 + tt];
      sg[0][br * 256 + tt] *= 1.f / (1.f + expf(-(a0 + bb)));
      sg[1][br * 256 + tt] *= 1.f / (1.f + expf(-(a1 + bb)));
    }
    __syncthreads();
    // ---- P3: rel fc1 768->256 relu ----
    {
      const float* wp = Wc1 + tt;
      const float* x0 = &sg[0][0];
      const float* x1 = &sg[1][0];
      float a0 = 0.f, a1 = 0.f;
      for (int k8 = 0; k8 < 96; ++k8) DOT8(wp, 256, x0, x1, k8 * 8, a0, a1)
      float bb = bc1[tt];
      h2[0][tt] = fmaxf(a0 + bb, 0.f);
      h2[1][tt] = fmaxf(a1 + bb, 0.f);
    }
    __syncthreads();
    // ---- P4: rel fc2 -> relf + stash ----
    {
      const float* wp = Wc2 + tt;
      const float* x0 = &h2[0][0];
      const float* x1 = &h2[1][0];
      float a0 = 0.f, a1 = 0.f;
      for (int k8 = 0; k8 < 32; ++k8) DOT8(wp, 256, x0, x1, k8 * 8, a0, a1)
      float bb = bc2[tt];
      float v0 = a0 + bb, v1 = a1 + bb;
      relf[(size_t)r0 * DD + tt] = v0;
      relf[(size_t)(r0 + 1) * DD + tt] = v1;
      rf[0][tt] = v0; rf[1][tt] = v1;
    }
    __syncthreads();
    // ---- P5: H_rel = relf @ Wg ----
    {
      const float* wp = Wg + tt;
      const float* x0 = &rf[0][0];
      const float* x1 = &rf[1][0];
      float a0 = 0.f, a1 = 0.f;
      for (int k8 = 0; k8 < 32; ++k8) DOT8(wp, 256, x0, x1, k8 * 8, a0, a1)
      H[(size_t)(NOBJ + r0) * DD + tt] = a0;
      H[(size_t)(NOBJ + r0 + 1) * DD + tt] = a1;
    }
  } else {
    // ---- emb2 + H_obj: 1 object per block, coalesced original W2/Wg ----
    const int i = b - NP / 2;   // 0..31
    float s[8];
#pragma unroll
    for (int u = 0; u < 8; ++u) s[u] = 0.f;
#pragma unroll
    for (int c0 = 0; c0 < CH; c0 += 8) {
#pragma unroll
      for (int u = 0; u < 8; ++u)
        s[u] += part[(size_t)(c0 + u) * (NOBJ * DD) + i * DD + t];
    }
    float tot = ((s[0] + s[1]) + (s[2] + s[3])) + ((s[4] + s[5]) + (s[6] + s[7]));
    hob[t] = fmaxf(tot + b1[t], 0.f);
    __syncthreads();
    {
      float a = 0.f;
#pragma unroll 4
      for (int k4 = 0; k4 < 64; ++k4) {
        float4 hv = *((const float4*)hob + k4);
        int k = 4 * k4;
        a += hv.x * W2[k * 256 + t]       + hv.y * W2[(k + 1) * 256 + t]
           + hv.z * W2[(k + 2) * 256 + t] + hv.w * W2[(k + 3) * 256 + t];
      }
      float v = a + b2[t];
      objf[i * DD + t] = v;
      eob[t] = v;
    }
    __syncthreads();
    {
      float a = 0.f;
#pragma unroll 4
      for (int k4 = 0; k4 < 64; ++k4) {
        float4 ev = *((const float4*)eob + k4);
        int k = 4 * k4;
        a += ev.x * Wg[k * 256 + t]       + ev.y * Wg[(k + 1) * 256 + t]
           + ev.z * Wg[(k + 2) * 256 + t] + ev.w * Wg[(k + 3) * 256 + t];
      }
      H[(size_t)i * DD + t] = a;
    }
  }
}

// ============ K_HEADS: rel(0..247, 4 pairs) + obj(248..279), 1024 thr ======
__global__ void __launch_bounds__(1024, 1)
k_heads(const float* __restrict__ H, const float* __restrict__ objf,
        const float* __restrict__ relf, const int* __restrict__ pairs,
        const float* __restrict__ bg,
        const float* __restrict__ WopT, const float* __restrict__ bop,
        const float* __restrict__ WrpT, const float* __restrict__ brp,
        float* __restrict__ out) {
  const int b = blockIdx.x, t = threadIdx.x;
  const int p = t >> 8, tt = t & 255;
  if (b < NP / 4) {
    __shared__ __align__(16) float gr[4][DD];
    __shared__ float red[4][4][64];
    const int r = b * 4 + p;
    int si = pairs[2 * r], oi = pairs[2 * r + 1];
    float hsum = H[si * DD + tt] + H[oi * DD + tt] + H[(size_t)(NOBJ + r) * DD + tt];
    gr[p][tt] = fmaxf(hsum * (1.f / 3.f) + bg[tt], 0.f) + relf[(size_t)r * DD + tt];
    __syncthreads();
    const int q = tt >> 6, c = tt & 63;
    float a = 0.f;
    if (c < RC) {
      const float4* w4 = (const float4*)(WrpT + c * 256 + q * 64);
#pragma unroll
      for (int j = 0; j < 16; ++j) {
        float4 wv = w4[j];
        float4 gv = *(const float4*)&gr[p][q * 64 + 4 * j];
        a += gv.x * wv.x + gv.y * wv.y + gv.z * wv.z + gv.w * wv.w;
      }
    }
    red[p][q][c] = a;
    __syncthreads();
    if (tt < RC)
      out[NOBJ * OC + (size_t)r * RC + tt] =
          red[p][0][tt] + red[p][1][tt] + red[p][2][tt] + red[p][3][tt] + brp[tt];
  } else {
    const int i = b - NP / 4;   // 0..31
    const int slice = p;
    __shared__ int2 pr[NP];
    __shared__ float red2[4][DD];
    __shared__ __align__(16) float gro[DD];
    const int2* p2 = (const int2*)pairs;
    for (int r = t; r < NP; r += 1024) pr[r] = p2[r];
    __syncthreads();
    float acc = 0.f;
    if (slice == 0) {
#pragma unroll 8
      for (int j = 0; j < NOBJ; ++j) acc += H[j * DD + tt];
    }
    const int rbeg = slice * 248;
#pragma unroll 8
    for (int r = rbeg; r < rbeg + 248; ++r) {
      int2 q = pr[r];
      float v = H[(size_t)(NOBJ + r) * DD + tt];
      if (q.x == i || q.y == i) acc += v;
    }
    red2[slice][tt] = acc;
    __syncthreads();
    if (t < DD) {
      float pre = (red2[0][t] + red2[1][t] + red2[2][t] + red2[3][t]) * (1.f / 94.f);
      gro[t] = fmaxf(pre + bg[t], 0.f) + objf[i * DD + t];
    }
    __syncthreads();
    float hsum = 0.f;
    if (tt < OC) {
      const float4* w4 = (const float4*)(WopT + tt * 256 + slice * 64);
#pragma unroll
      for (int j = 0; j < 16; ++j) {
        float4 wv = w4[j];
        float4 gv = *(const float4*)&gro[slice * 64 + 4 * j];
        hsum += gv.x * wv.x + gv.y * wv.y + gv.z * wv.z + gv.w * wv.w;
      }
    }
    red2[slice][tt] = hsum;
    __syncthreads();
    if (t < OC)
      out[i * OC + t] = red2[0][t] + red2[1][t] + red2[2][t] + red2[3][t] + bop[t];
  }
}

extern "C" void kernel_launch(void* const* d_in, const int* in_sizes, int n_in,
                              void* d_out, int out_size, void* d_ws, size_t ws_size,
                              hipStream_t stream) {
  const float* roi   = (const float*)d_in[0];
  const float* bbox  = (const float*)d_in[1];
  const float* logit = (const float*)d_in[2];
  const float* uf    = (const float*)d_in[3];
  const int*   pairs = (const int*)d_in[4];
  const float* W1    = (const float*)d_in[5];
  const float* b1    = (const float*)d_in[6];
  const float* W2    = (const float*)d_in[7];
  const float* b2    = (const float*)d_in[8];
  const float* fc1w  = (const float*)d_in[9];
  const float* fc1b  = (const float*)d_in[10];
  const float* fc2w  = (const float*)d_in[11];
  const float* fc2b  = (const float*)d_in[12];
  const float* Wc1   = (const float*)d_in[13];
  const float* bc1   = (const float*)d_in[14];
  const float* Wc2   = (const float*)d_in[15];
  const float* bc2   = (const float*)d_in[16];
  const float* Wg    = (const float*)d_in[17];
  const float* bg    = (const float*)d_in[18];
  const float* Wop   = (const float*)d_in[19];
  const float* bop   = (const float*)d_in[20];
  const float* Wrp   = (const float*)d_in[21];
  const float* brp   = (const float*)d_in[22];

  float* ws    = (float*)d_ws;
  float* part  = ws + OFF_PART;
  float* objf  = ws + OFF_OBJF;
  float* sAll  = ws + OFF_SALL;
  float* relf  = ws + OFF_RELF;
  float* Hbuf  = ws + OFF_H;
  float* WopT  = ws + OFF_WOPT;
  float* WrpT  = ws + OFF_WRPT;
  float* out   = (float*)d_out;

  k_pre<<<NP + CH + 64, 256, 0, stream>>>(uf, bbox, pairs, roi, logit, W1,
                                          Wop, Wrp, sAll, part, WopT, WrpT);
  k_mid2<<<NP / 2 + NOBJ, 256, 0, stream>>>(sAll, fc1w, fc1b, fc2w, fc2b,
                                            Wc1, bc1, Wc2, bc2, Wg,
                                            part, b1, W2, b2, relf, objf, Hbuf);
  k_heads<<<NP / 4 + NOBJ, 1024, 0, stream>>>(Hbuf, objf, relf, pairs, bg,
                                              WopT, bop, WrpT, brp, out);
}